// Round 4
// baseline (214.065 us; speedup 1.0000x reference)
//
#include <hip/hip_runtime.h>
#include <hip/hip_bf16.h>

#define D 64            // D_IN == D_OUT == 64
#define K 24            // slots/node; deg~Poisson(10): P(>24)~3e-5 -> ~10 spill edges (inline, exact)
#define M44 ((1ULL << 44) - 1)
#define SPILLCAP 65536

typedef __attribute__((ext_vector_type(4))) _Float16 half4;
typedef __attribute__((ext_vector_type(8))) _Float16 half8;
typedef __attribute__((ext_vector_type(4))) float f32x4;   // nontemporal-store-able

// ---------------------------------------------------------------------------
// k_build v3: XCD-affine row-parity build (r1-PROVEN: WRITE 61MB->off-radar)
// FUSED with the x->fp16 conversion and W-transpose as trailing blocks (r2):
// build is atomic-wall-bound (11% BW, 1% VALU), so the streaming prep work
// hides under it instead of costing a serial ~6us dispatch (r1 lesson: the
// gather win was eaten by k_xhalf's serial time).
// Build partition: block b<buildBlocks handles edge chunk b>>3 filtered to
// rows (r&7)==(b&7) — exact partition; blockIdx round-robin pins each row's
// slot lines to ONE XCD L2 (single dirty copy, no writeback fight with the
// 1M device atomics). MEASURED WALLS: ~21.5G RMW/s atomics; 1 edge/thread.
__global__ __launch_bounds__(256) void k_build(const int* __restrict__ rowi,
                                               const int* __restrict__ coli,
                                               const float* __restrict__ ew,
                                               unsigned long long* __restrict__ packed,
                                               unsigned int* __restrict__ slots,
                                               int4* __restrict__ spill,
                                               int* __restrict__ spillCnt, int nE,
                                               int buildBlocks,
                                               const float4* __restrict__ x4,
                                               half8* __restrict__ xh8, int nv,
                                               const float* __restrict__ W,
                                               float* __restrict__ Wt, int useH) {
    int b = blockIdx.x;
    if (b < buildBlocks) {
        int p = b & 7;                      // parity class this block serves
        int e = (b >> 3) * 256 + threadIdx.x;
        if (e >= nE) return;
        int r = rowi[e];
        if ((r & 7) != p) return;           // owned by the copy on the right XCD
        int c = coli[e];
        float w = ew[e];
        unsigned long long fx = (unsigned long long)((double)w * 4294967296.0);
        unsigned long long old = atomicAdd(&packed[r], (1ULL << 44) | fx);
        int rank = (int)(old >> 44);
        if (rank < K) {
            int q = (int)(w * 32768.0f + 0.5f);
            if (q > 32767) q = 32767;
            slots[r * K + rank] = ((unsigned int)c << 15) | (unsigned int)q;
        } else {
            int pI = atomicAdd(spillCnt, 1);
            if (pI < SPILLCAP) spill[pI] = make_int4(r, c, __float_as_int(w), 0);
        }
        return;
    }
    int pb = b - buildBlocks;
    if (pb == 0) {
        // W-transpose: Wt[k][o] = W[o][k]  (16KB, one block, trivial)
        for (int idx = threadIdx.x; idx < D * D; idx += 256) {
            int o = idx >> 6, k = idx & 63;
            Wt[k * D + o] = W[idx];
        }
        return;
    }
    // x fp32 -> fp16 (halves gather traffic; 12.8MB caches far better than
    // 25.6MB; 2^-11 rel err -> ~2e-4 on out, invisible at tolerance)
    int t = (pb - 1) * 256 + threadIdx.x;
    if (!useH || t >= nv) return;
    float4 a = x4[2 * t], bb = x4[2 * t + 1];
    half8 h;
    h[0] = (_Float16)a.x; h[1] = (_Float16)a.y; h[2] = (_Float16)a.z; h[3] = (_Float16)a.w;
    h[4] = (_Float16)bb.x; h[5] = (_Float16)bb.y; h[6] = (_Float16)bb.z; h[7] = (_Float16)bb.w;
    xh8[t] = h;
}

// lazy dis: rsqrt(1 + sum_ew) straight from the packed word.
__device__ __forceinline__ float dis_of(unsigned long long pk) {
    return rsqrtf(1.0f + (float)(pk & M44) * (1.0f / 4294967296.0f));
}

// k_gather_gemm v3 (r11-PROVEN grid: 6250 blocks, 1 node / 16-lane group).
// r2 theory: gather is LATENCY-bound on L2-miss requests (1.87 TB/s fetch at
// 34% VALU — no BW wall), and occupancy was pinned at ~67% because
// LDS 20480B x 8 blocks == exactly 160KiB (granularity -> 7 blocks/CU).
// Fixes:
//  (a) Bs (16KB W tile) REMOVED from LDS. W is uniform across blocks and
//      L1/L2-resident; phase 2 reads pre-transposed Wt with coalesced
//      float4 loads. LDS/block 20KB->4KB -> occupancy cap = 32 waves/CU.
//  (b) slots loads NONTEMPORAL (read exactly once; stop evicting x from L2
//      — r1 measured x hit rate ~10%). out stores nontemporal (25MB stream).
//  (c) packed stays cached (800KB, ~10x reuse as neighbor-dis).
template <bool H>
__global__ __launch_bounds__(256) void k_gather_gemm(const float* __restrict__ x,
                                                     const _Float16* __restrict__ xh,
                                                     const unsigned long long* __restrict__ packed,
                                                     const unsigned int* __restrict__ slots,
                                                     const int4* __restrict__ spill,
                                                     const int* __restrict__ spillCnt,
                                                     const float* __restrict__ Wt,
                                                     const float* __restrict__ bias,
                                                     float* __restrict__ out, int n) {
    __shared__ float Ast[16 * D];      // 4 KB: 16-row A tile, swizzled slots
    float4* Ast4 = (float4*)Ast;
    int tid = threadIdx.x;

    // Phase 1: gather (one node per 16-lane group)
    int j   = tid & 15;                // k-chunk lane
    int grp = tid >> 4;                // 0..15
    int i0  = blockIdx.x * 16;
    int i   = i0 + grp;

    float4 acc = make_float4(0.f, 0.f, 0.f, 0.f);
    const float4* x4 = (const float4*)x;
    const half4*  xh4 = (const half4*)xh;
    if (i < n) {
        unsigned long long pk = packed[i];
        int rawc = (int)(pk >> 44);
        int c_n = rawc < K ? rawc : K;
        int s = i * K;
        for (int off = 0; off < c_n; off += 16) {
            int idx = off + j;
            unsigned int rec = 0u;
            float wj = 0.f;
            if (idx < c_n) {
                rec = __builtin_nontemporal_load(&slots[s + idx]);
                wj = (float)(rec & 32767u) * (1.0f / 32768.0f) * dis_of(packed[rec >> 15]);
            }
            int mm = c_n - off; if (mm > 16) mm = 16;
#pragma unroll
            for (int t = 0; t < 16; ++t) {
                if (t < mm) {
                    int col = (int)((unsigned int)__shfl((int)rec, t, 16) >> 15);
                    float w = __shfl(wj, t, 16);
                    if constexpr (H) {
                        half4 hv = xh4[col * 16 + j];
                        acc.x += w * (float)hv[0]; acc.y += w * (float)hv[1];
                        acc.z += w * (float)hv[2]; acc.w += w * (float)hv[3];
                    } else {
                        float4 xv = x4[col * 16 + j];
                        acc.x += w * xv.x; acc.y += w * xv.y;
                        acc.z += w * xv.z; acc.w += w * xv.w;
                    }
                }
            }
        }
        if (rawc > K) {                // statistically ~10 edges in the graph
            int total = *spillCnt;
            if (total > SPILLCAP) total = SPILLCAP;
            for (int sp = 0; sp < total; ++sp) {
                int4 v = spill[sp];    // broadcast (same addr all lanes)
                if (v.x == i) {
                    float w = __int_as_float(v.z) * dis_of(packed[v.y]);
                    if constexpr (H) {
                        half4 hv = xh4[v.y * 16 + j];
                        acc.x += w * (float)hv[0]; acc.y += w * (float)hv[1];
                        acc.z += w * (float)hv[2]; acc.w += w * (float)hv[3];
                    } else {
                        float4 xv = x4[v.y * 16 + j];
                        acc.x += w * xv.x; acc.y += w * xv.y;
                        acc.z += w * xv.z; acc.w += w * xv.w;
                    }
                }
            }
        }
        float di = dis_of(pk);
        if constexpr (H) {
            half4 hi = xh4[i * 16 + j];
            acc.x = di * (di * (float)hi[0] + acc.x);
            acc.y = di * (di * (float)hi[1] + acc.y);
            acc.z = di * (di * (float)hi[2] + acc.z);
            acc.w = di * (di * (float)hi[3] + acc.w);
        } else {
            float4 xi = x4[i * 16 + j];
            acc.x = di * (di * xi.x + acc.x);
            acc.y = di * (di * xi.y + acc.y);
            acc.z = di * (di * xi.z + acc.z);
            acc.w = di * (di * xi.w + acc.w);
        }
    }
    Ast4[grp * 16 + ((j + (grp >> 2)) & 15)] = acc;   // swizzled slot
    __syncthreads();                   // covers the Ast tile only now

    // Phase 2: 16x64 mini-GEMM; B read straight from Wt (L1/L2-resident,
    // coalesced: lanes of a wave read consecutive float4s of a Wt row).
    int row = tid >> 4;
    int cg  = tid & 15;
    const float4* Wt4 = (const float4*)Wt;
    float4 oacc = ((const float4*)bias)[cg];
#pragma unroll 4
    for (int kc = 0; kc < 16; ++kc) {
        float4 a4 = Ast4[row * 16 + ((kc + (row >> 2)) & 15)];
        float4 b0 = Wt4[(4 * kc + 0) * 16 + cg];
        float4 b1 = Wt4[(4 * kc + 1) * 16 + cg];
        float4 b2 = Wt4[(4 * kc + 2) * 16 + cg];
        float4 b3 = Wt4[(4 * kc + 3) * 16 + cg];
        oacc.x += a4.x * b0.x + a4.y * b1.x + a4.z * b2.x + a4.w * b3.x;
        oacc.y += a4.x * b0.y + a4.y * b1.y + a4.z * b2.y + a4.w * b3.y;
        oacc.z += a4.x * b0.z + a4.y * b1.z + a4.z * b2.z + a4.w * b3.z;
        oacc.w += a4.x * b0.w + a4.y * b1.w + a4.z * b2.w + a4.w * b3.w;
    }
    int r = i0 + row;
    if (r < n) {
        f32x4 o4 = { oacc.x, oacc.y, oacc.z, oacc.w };
        __builtin_nontemporal_store(o4, &((f32x4*)out)[r * 16 + cg]);
    }
}

extern "C" void kernel_launch(void* const* d_in, const int* in_sizes, int n_in,
                              void* d_out, int out_size, void* d_ws, size_t ws_size,
                              hipStream_t stream) {
    const float* x    = (const float*)d_in[0];
    const int*   ei   = (const int*)d_in[1];   // [2*E] flat: rows then cols
    const float* ew   = (const float*)d_in[2];
    const float* W    = (const float*)d_in[3];
    const float* bias = (const float*)d_in[4];
    float* out = (float*)d_out;

    int n  = in_sizes[0] / D;   // 100000
    int nE = in_sizes[2];       // 1000000
    const int* rowi = ei;
    const int* coli = ei + nE;

    // workspace: packed | spillCnt | slots | spill | Wt | xh(fp16)
    char* w = (char*)d_ws;
    unsigned long long* packed = (unsigned long long*)w; w += (size_t)n * 8;
    int* spillCnt = (int*)w;                             w += 64;
    unsigned int* slots = (unsigned int*)w;              w += (size_t)n * K * 4;
    int4* spill = (int4*)w;                              w += (size_t)SPILLCAP * 16;
    float* Wt = (float*)w;                               w += (size_t)D * D * 4;
    _Float16* xh = (_Float16*)w;

    size_t need = (size_t)n * 8 + 64 + (size_t)n * K * 4 + (size_t)SPILLCAP * 16
                + (size_t)D * D * 4 + (size_t)n * D * 2;
    int useH = ws_size >= need ? 1 : 0;

    int gE = (nE + 255) / 256;
    int buildBlocks = gE * 8;
    int nv = n * D / 8;         // 800000 half8s
    int prepBlocks = 1 + (useH ? (nv + 255) / 256 : 0);
    int gT = (n + 15) / 16;     // 6250 blocks: 16 nodes/block, 1 node/group

    hipMemsetAsync(packed, 0, (size_t)n * 8 + 64, stream);   // packed + spillCnt
    k_build<<<buildBlocks + prepBlocks, 256, 0, stream>>>(
        rowi, coli, ew, packed, slots, spill, spillCnt, nE,
        buildBlocks, (const float4*)x, (half8*)xh, nv, W, Wt, useH);
    if (useH)
        k_gather_gemm<true><<<gT, 256, 0, stream>>>(x, xh, packed, slots, spill, spillCnt, Wt, bias, out, n);
    else
        k_gather_gemm<false><<<gT, 256, 0, stream>>>(x, xh, packed, slots, spill, spillCnt, Wt, bias, out, n);
}

// Round 5
// 179.376 us; speedup vs baseline: 1.1934x; 1.1934x over previous
//
#include <hip/hip_runtime.h>
#include <hip/hip_bf16.h>

#define D 64            // D_IN == D_OUT == 64
#define K 24            // slots/node; deg~Poisson(10): P(>24)~3e-5 -> ~10 spill edges (inline, exact)
#define M44 ((1ULL << 44) - 1)
#define SPILLCAP 65536

typedef __attribute__((ext_vector_type(4))) _Float16 half4;
typedef __attribute__((ext_vector_type(8))) _Float16 half8;

// ---------------------------------------------------------------------------
// k_build v4: XCD-affine row-parity build (r1-PROVEN: WRITE 61MB->off-radar)
// fused with x->fp16 conversion as trailing blocks (r2 idea, kept: build is
// atomic-wall-bound at 11% BW / 1% VALU, so streaming prep hides under it
// instead of costing a serial ~6us dispatch).
// Partition: block b<buildBlocks handles edge chunk b>>3 filtered to rows
// (r&7)==(b&7) — exact partition; blockIdx round-robin pins each row's slot
// lines to ONE XCD L2 (single dirty copy; no writeback fight with the 1M
// device atomics). MEASURED WALLS: ~21.5G RMW/s atomics; 1 edge/thread.
__global__ __launch_bounds__(256) void k_build(const int* __restrict__ rowi,
                                               const int* __restrict__ coli,
                                               const float* __restrict__ ew,
                                               unsigned long long* __restrict__ packed,
                                               unsigned int* __restrict__ slots,
                                               int4* __restrict__ spill,
                                               int* __restrict__ spillCnt, int nE,
                                               int buildBlocks,
                                               const float4* __restrict__ x4,
                                               half8* __restrict__ xh8, int nv, int useH) {
    int b = blockIdx.x;
    if (b < buildBlocks) {
        int p = b & 7;                      // parity class this block serves
        int e = (b >> 3) * 256 + threadIdx.x;
        if (e >= nE) return;
        int r = rowi[e];
        if ((r & 7) != p) return;           // owned by the copy on the right XCD
        int c = coli[e];
        float w = ew[e];
        unsigned long long fx = (unsigned long long)((double)w * 4294967296.0);
        unsigned long long old = atomicAdd(&packed[r], (1ULL << 44) | fx);
        int rank = (int)(old >> 44);
        if (rank < K) {
            int q = (int)(w * 32768.0f + 0.5f);
            if (q > 32767) q = 32767;
            slots[r * K + rank] = ((unsigned int)c << 15) | (unsigned int)q;
        } else {
            int pI = atomicAdd(spillCnt, 1);
            if (pI < SPILLCAP) spill[pI] = make_int4(r, c, __float_as_int(w), 0);
        }
        return;
    }
    // trailing blocks: x fp32 -> fp16 (halves gather traffic; 2^-11 rel err
    // -> ~2e-4 on out, invisible at tolerance)
    int t = (b - buildBlocks) * 256 + threadIdx.x;
    if (!useH || t >= nv) return;
    float4 a = x4[2 * t], bb = x4[2 * t + 1];
    half8 h;
    h[0] = (_Float16)a.x; h[1] = (_Float16)a.y; h[2] = (_Float16)a.z; h[3] = (_Float16)a.w;
    h[4] = (_Float16)bb.x; h[5] = (_Float16)bb.y; h[6] = (_Float16)bb.z; h[7] = (_Float16)bb.w;
    xh8[t] = h;
}

// lazy dis: rsqrt(1 + sum_ew) straight from the packed word.
__device__ __forceinline__ float dis_of(unsigned long long pk) {
    return rsqrtf(1.0f + (float)(pk & M44) * (1.0f / 4294967296.0f));
}

// k_gather_gemm v4 = r1 structure (measured 61.5us: Bs in LDS w/ 2-way-bank
// staging swizzle, cached loads/stores) + BRANCH-FREE inner t-loop.
// r4 post-mortem: gather is latency*concurrency-bound (nt-bypass ADDED
// latency and throughput fell 1.87->1.35 TB/s — a BW wall wouldn't do that).
// Little's law at 61.5us: only ~2 x-rows in flight per wave, because each
// `if (t<mm)` guard compiled to an exec-branch with its own s_waitcnt ->
// one load at a time. Invalid lanes already have rec=0,wj=0, so the guarded
// body contributes EXACTLY zero when unguarded (w=0; col=0 reads the
// L1-resident row 0). Dropping the guard issues all 16 row-loads
// back-to-back: ~8x MLP on the same byte count.
template <bool H>
__global__ __launch_bounds__(256) void k_gather_gemm(const float* __restrict__ x,
                                                     const _Float16* __restrict__ xh,
                                                     const unsigned long long* __restrict__ packed,
                                                     const unsigned int* __restrict__ slots,
                                                     const int4* __restrict__ spill,
                                                     const int* __restrict__ spillCnt,
                                                     const float* __restrict__ W,
                                                     const float* __restrict__ bias,
                                                     float* __restrict__ out, int n) {
    __shared__ float Bs[D * D];        // 16 KB: Bs[k][o] = W[o][k], swizzled s(k)=k>>2
    __shared__ float Ast[16 * D];      // 4 KB: 16-row A tile, swizzled slots
    float4* Ast4 = (float4*)Ast;
    int tid = threadIdx.x;

    // Phase 0: stage W (issue first; overlaps the gather's global loads).
    // Chunk-swizzle by kc -> exactly 2 lanes/bank on ds_write (free, m136).
    const float4* W4 = (const float4*)W;
#pragma unroll
    for (int v = 0; v < 4; ++v) {
        int idx = tid + v * 256;       // 0..1023
        int o  = idx >> 4;             // out-ch 0..63
        int kc = idx & 15;
        float4 wv = W4[idx];
        int gq = o >> 2, oo = o & 3;
        int cpos = 4 * ((gq + kc) & 15) + oo;
        Bs[(4 * kc + 0) * 64 + cpos] = wv.x;
        Bs[(4 * kc + 1) * 64 + cpos] = wv.y;
        Bs[(4 * kc + 2) * 64 + cpos] = wv.z;
        Bs[(4 * kc + 3) * 64 + cpos] = wv.w;
    }

    // Phase 1: gather (one node per 16-lane group)
    int j   = tid & 15;                // k-chunk lane
    int grp = tid >> 4;                // 0..15
    int i0  = blockIdx.x * 16;
    int i   = i0 + grp;

    float4 acc = make_float4(0.f, 0.f, 0.f, 0.f);
    const float4* x4 = (const float4*)x;
    const half4*  xh4 = (const half4*)xh;
    if (i < n) {
        unsigned long long pk = packed[i];
        int rawc = (int)(pk >> 44);
        int c_n = rawc < K ? rawc : K;
        int s = i * K;
        for (int off = 0; off < c_n; off += 16) {
            int idx = off + j;
            unsigned int rec = 0u;
            float wj = 0.f;
            if (idx < c_n) {           // invalid lanes: rec=0, wj=0 (must NOT
                rec = slots[s + idx];  // read stale slots beyond c_n)
                wj = (float)(rec & 32767u) * (1.0f / 32768.0f) * dis_of(packed[rec >> 15]);
            }
            // BRANCH-FREE: all 16 iterations run; invalid t has w=0 (adds 0)
            // and col=0 (x row 0, L1-resident broadcast). Loads issue
            // back-to-back -> full MLP.
#pragma unroll
            for (int t = 0; t < 16; ++t) {
                int col = (int)((unsigned int)__shfl((int)rec, t, 16) >> 15);
                float w = __shfl(wj, t, 16);
                if constexpr (H) {
                    half4 hv = xh4[col * 16 + j];
                    acc.x += w * (float)hv[0]; acc.y += w * (float)hv[1];
                    acc.z += w * (float)hv[2]; acc.w += w * (float)hv[3];
                } else {
                    float4 xv = x4[col * 16 + j];
                    acc.x += w * xv.x; acc.y += w * xv.y;
                    acc.z += w * xv.z; acc.w += w * xv.w;
                }
            }
        }
        if (rawc > K) {                // statistically ~10 edges in the graph
            int total = *spillCnt;
            if (total > SPILLCAP) total = SPILLCAP;
            for (int sp = 0; sp < total; ++sp) {
                int4 v = spill[sp];    // broadcast (same addr all lanes)
                if (v.x == i) {
                    float w = __int_as_float(v.z) * dis_of(packed[v.y]);
                    if constexpr (H) {
                        half4 hv = xh4[v.y * 16 + j];
                        acc.x += w * (float)hv[0]; acc.y += w * (float)hv[1];
                        acc.z += w * (float)hv[2]; acc.w += w * (float)hv[3];
                    } else {
                        float4 xv = x4[v.y * 16 + j];
                        acc.x += w * xv.x; acc.y += w * xv.y;
                        acc.z += w * xv.z; acc.w += w * xv.w;
                    }
                }
            }
        }
        float di = dis_of(pk);
        if constexpr (H) {
            half4 hi = xh4[i * 16 + j];
            acc.x = di * (di * (float)hi[0] + acc.x);
            acc.y = di * (di * (float)hi[1] + acc.y);
            acc.z = di * (di * (float)hi[2] + acc.z);
            acc.w = di * (di * (float)hi[3] + acc.w);
        } else {
            float4 xi = x4[i * 16 + j];
            acc.x = di * (di * xi.x + acc.x);
            acc.y = di * (di * xi.y + acc.y);
            acc.z = di * (di * xi.z + acc.z);
            acc.w = di * (di * xi.w + acc.w);
        }
    }
    Ast4[grp * 16 + ((j + (grp >> 2)) & 15)] = acc;   // swizzled slot
    __syncthreads();                   // covers Bs staging + Ast tile

    // Phase 2: 16x64 mini-GEMM (thread: row=grp', out-chs 4j..4j+3)
    int row = tid >> 4;
    int cg  = tid & 15;
    float4 oacc = ((const float4*)bias)[cg];
#pragma unroll 4
    for (int kc = 0; kc < 16; ++kc) {
        float4 a4 = Ast4[row * 16 + ((kc + (row >> 2)) & 15)];
        int cp = 4 * ((cg + kc) & 15);             // read swizzle matches staging
        float4 b0 = *(const float4*)&Bs[(4 * kc + 0) * 64 + cp];
        float4 b1 = *(const float4*)&Bs[(4 * kc + 1) * 64 + cp];
        float4 b2 = *(const float4*)&Bs[(4 * kc + 2) * 64 + cp];
        float4 b3 = *(const float4*)&Bs[(4 * kc + 3) * 64 + cp];
        oacc.x += a4.x * b0.x + a4.y * b1.x + a4.z * b2.x + a4.w * b3.x;
        oacc.y += a4.x * b0.y + a4.y * b1.y + a4.z * b2.y + a4.w * b3.y;
        oacc.z += a4.x * b0.z + a4.y * b1.z + a4.z * b2.z + a4.w * b3.z;
        oacc.w += a4.x * b0.w + a4.y * b1.w + a4.z * b2.w + a4.w * b3.w;
    }
    int r = i0 + row;
    if (r < n) ((float4*)out)[r * 16 + cg] = oacc;
}

extern "C" void kernel_launch(void* const* d_in, const int* in_sizes, int n_in,
                              void* d_out, int out_size, void* d_ws, size_t ws_size,
                              hipStream_t stream) {
    const float* x    = (const float*)d_in[0];
    const int*   ei   = (const int*)d_in[1];   // [2*E] flat: rows then cols
    const float* ew   = (const float*)d_in[2];
    const float* W    = (const float*)d_in[3];
    const float* bias = (const float*)d_in[4];
    float* out = (float*)d_out;

    int n  = in_sizes[0] / D;   // 100000
    int nE = in_sizes[2];       // 1000000
    const int* rowi = ei;
    const int* coli = ei + nE;

    // workspace: packed | spillCnt | slots | spill | xh(fp16)
    char* w = (char*)d_ws;
    unsigned long long* packed = (unsigned long long*)w; w += (size_t)n * 8;
    int* spillCnt = (int*)w;                             w += 64;
    unsigned int* slots = (unsigned int*)w;              w += (size_t)n * K * 4;
    int4* spill = (int4*)w;                              w += (size_t)SPILLCAP * 16;
    _Float16* xh = (_Float16*)w;

    size_t need = (size_t)n * 8 + 64 + (size_t)n * K * 4 + (size_t)SPILLCAP * 16
                + (size_t)n * D * 2;
    int useH = ws_size >= need ? 1 : 0;

    int gE = (nE + 255) / 256;
    int buildBlocks = gE * 8;
    int nv = n * D / 8;         // 800000 half8s
    int prepBlocks = useH ? (nv + 255) / 256 : 0;
    int gT = (n + 15) / 16;     // 6250 blocks: 16 nodes/block, 1 node/group

    hipMemsetAsync(packed, 0, (size_t)n * 8 + 64, stream);   // packed + spillCnt
    k_build<<<buildBlocks + prepBlocks, 256, 0, stream>>>(
        rowi, coli, ew, packed, slots, spill, spillCnt, nE,
        buildBlocks, (const float4*)x, (half8*)xh, nv, useH);
    if (useH)
        k_gather_gemm<true><<<gT, 256, 0, stream>>>(x, xh, packed, slots, spill, spillCnt, W, bias, out, n);
    else
        k_gather_gemm<false><<<gT, 256, 0, stream>>>(x, xh, packed, slots, spill, spillCnt, W, bias, out, n);
}

// Round 6
// 175.695 us; speedup vs baseline: 1.2184x; 1.0209x over previous
//
#include <hip/hip_runtime.h>
#include <hip/hip_bf16.h>

#define D 64            // D_IN == D_OUT == 64
#define K 24            // slots/node; deg~Poisson(10): P(>24)~3e-5 -> ~10 spill edges (inline, exact)
#define M44 ((1ULL << 44) - 1)
#define SPILLCAP 65536

typedef __attribute__((ext_vector_type(4))) _Float16 half4;
typedef __attribute__((ext_vector_type(8))) _Float16 half8;

// ---------------------------------------------------------------------------
// k_build v5: XCD-affine row-parity build (r1-PROVEN) + x->fp16 prep blocks
// INTERLEAVED AT THE FRONT of the grid (r5 post-mortem: trailing prep blocks
// ran serialized in the kernel tail — fused build ≈ build + prep, no overlap.
// Leading prep blocks co-reside with atomic-bound build blocks: streaming
// pipe and atomic pipe overlap, m114-style).
// Build partition: block b' = b - prepBlocks handles edge chunk b'>>3
// filtered to rows (r&7)==(b'&7) — exact partition. XCD of that block is
// (p + prepBlocks)&7: still ONE fixed XCD per parity class (affinity holds,
// just permuted). MEASURED WALLS: ~21.5G RMW/s device atomics -> 46.5us
// floor for 1M edges; 1 edge/thread (r10); separate dispatches (r12).
__global__ __launch_bounds__(256) void k_build(const int* __restrict__ rowi,
                                               const int* __restrict__ coli,
                                               const float* __restrict__ ew,
                                               unsigned long long* __restrict__ packed,
                                               unsigned int* __restrict__ slots,
                                               int4* __restrict__ spill,
                                               int* __restrict__ spillCnt, int nE,
                                               int prepBlocks,
                                               const float4* __restrict__ x4,
                                               half8* __restrict__ xh8, int nv) {
    int b = blockIdx.x;
    if (b < prepBlocks) {
        // leading blocks: x fp32 -> fp16 (halves gather traffic; 2^-11 rel
        // err -> ~2e-4 on out, invisible at tolerance)
        int t = b * 256 + threadIdx.x;
        if (t >= nv) return;
        float4 a = x4[2 * t], bb = x4[2 * t + 1];
        half8 h;
        h[0] = (_Float16)a.x; h[1] = (_Float16)a.y; h[2] = (_Float16)a.z; h[3] = (_Float16)a.w;
        h[4] = (_Float16)bb.x; h[5] = (_Float16)bb.y; h[6] = (_Float16)bb.z; h[7] = (_Float16)bb.w;
        xh8[t] = h;
        return;
    }
    int bp = b - prepBlocks;
    int p = bp & 7;                     // parity class this block serves
    int e = (bp >> 3) * 256 + threadIdx.x;
    if (e >= nE) return;
    int r = rowi[e];
    if ((r & 7) != p) return;           // owned by the sibling on the right XCD
    int c = coli[e];
    float w = ew[e];
    unsigned long long fx = (unsigned long long)((double)w * 4294967296.0);
    unsigned long long old = atomicAdd(&packed[r], (1ULL << 44) | fx);
    int rank = (int)(old >> 44);
    if (rank < K) {
        int q = (int)(w * 32768.0f + 0.5f);
        if (q > 32767) q = 32767;
        slots[r * K + rank] = ((unsigned int)c << 15) | (unsigned int)q;
    } else {
        int pI = atomicAdd(spillCnt, 1);
        if (pI < SPILLCAP) spill[pI] = make_int4(r, c, __float_as_int(w), 0);
    }
}

// lazy dis: rsqrt(1 + sum_ew) straight from the packed word.
__device__ __forceinline__ float dis_of(unsigned long long pk) {
    return rsqrtf(1.0f + (float)(pk & M44) * (1.0f / 4294967296.0f));
}

// k_gather_gemm v5 = r4-PROVEN structure (Bs in LDS w/ 2-way-bank staging
// swizzle, cached loads/stores, BRANCH-FREE inner t-loop: invalid t has w=0
// and col=0 -> contributes exactly zero; 16 row-loads issue back-to-back for
// full MLP — r5 measured: gather left top-5, <57us).
// r5 micro: self-row xh load + packed[i] hoisted to the top so the epilogue
// loads are in flight during the whole slot loop.
template <bool H>
__global__ __launch_bounds__(256) void k_gather_gemm(const float* __restrict__ x,
                                                     const _Float16* __restrict__ xh,
                                                     const unsigned long long* __restrict__ packed,
                                                     const unsigned int* __restrict__ slots,
                                                     const int4* __restrict__ spill,
                                                     const int* __restrict__ spillCnt,
                                                     const float* __restrict__ W,
                                                     const float* __restrict__ bias,
                                                     float* __restrict__ out, int n) {
    __shared__ float Bs[D * D];        // 16 KB: Bs[k][o] = W[o][k], swizzled s(k)=k>>2
    __shared__ float Ast[16 * D];      // 4 KB: 16-row A tile, swizzled slots
    float4* Ast4 = (float4*)Ast;
    int tid = threadIdx.x;

    // Phase 0: stage W (issue first; overlaps the gather's global loads).
    // Chunk-swizzle by kc -> exactly 2 lanes/bank on ds_write (free, m136).
    const float4* W4 = (const float4*)W;
#pragma unroll
    for (int v = 0; v < 4; ++v) {
        int idx = tid + v * 256;       // 0..1023
        int o  = idx >> 4;             // out-ch 0..63
        int kc = idx & 15;
        float4 wv = W4[idx];
        int gq = o >> 2, oo = o & 3;
        int cpos = 4 * ((gq + kc) & 15) + oo;
        Bs[(4 * kc + 0) * 64 + cpos] = wv.x;
        Bs[(4 * kc + 1) * 64 + cpos] = wv.y;
        Bs[(4 * kc + 2) * 64 + cpos] = wv.z;
        Bs[(4 * kc + 3) * 64 + cpos] = wv.w;
    }

    // Phase 1: gather (one node per 16-lane group)
    int j   = tid & 15;                // k-chunk lane
    int grp = tid >> 4;                // 0..15
    int i0  = blockIdx.x * 16;
    int i   = i0 + grp;

    float4 acc = make_float4(0.f, 0.f, 0.f, 0.f);
    const float4* x4 = (const float4*)x;
    const half4*  xh4 = (const half4*)xh;
    if (i < n) {
        unsigned long long pk = packed[i];
        // hoisted self-row load: in flight during the whole slot loop
        half4 hi; float4 xi;
        if constexpr (H) hi = xh4[i * 16 + j]; else xi = x4[i * 16 + j];
        int rawc = (int)(pk >> 44);
        int c_n = rawc < K ? rawc : K;
        int s = i * K;
        for (int off = 0; off < c_n; off += 16) {
            int idx = off + j;
            unsigned int rec = 0u;
            float wj = 0.f;
            if (idx < c_n) {           // invalid lanes: rec=0, wj=0 (must NOT
                rec = slots[s + idx];  // read stale slots beyond c_n)
                wj = (float)(rec & 32767u) * (1.0f / 32768.0f) * dis_of(packed[rec >> 15]);
            }
            // BRANCH-FREE: all 16 iterations run; invalid t has w=0 (adds 0)
            // and col=0 (x row 0, L1-resident broadcast). Loads issue
            // back-to-back -> full MLP.
#pragma unroll
            for (int t = 0; t < 16; ++t) {
                int col = (int)((unsigned int)__shfl((int)rec, t, 16) >> 15);
                float w = __shfl(wj, t, 16);
                if constexpr (H) {
                    half4 hv = xh4[col * 16 + j];
                    acc.x += w * (float)hv[0]; acc.y += w * (float)hv[1];
                    acc.z += w * (float)hv[2]; acc.w += w * (float)hv[3];
                } else {
                    float4 xv = x4[col * 16 + j];
                    acc.x += w * xv.x; acc.y += w * xv.y;
                    acc.z += w * xv.z; acc.w += w * xv.w;
                }
            }
        }
        if (rawc > K) {                // statistically ~10 edges in the graph
            int total = *spillCnt;
            if (total > SPILLCAP) total = SPILLCAP;
            for (int sp = 0; sp < total; ++sp) {
                int4 v = spill[sp];    // broadcast (same addr all lanes)
                if (v.x == i) {
                    float w = __int_as_float(v.z) * dis_of(packed[v.y]);
                    if constexpr (H) {
                        half4 hv = xh4[v.y * 16 + j];
                        acc.x += w * (float)hv[0]; acc.y += w * (float)hv[1];
                        acc.z += w * (float)hv[2]; acc.w += w * (float)hv[3];
                    } else {
                        float4 xv = x4[v.y * 16 + j];
                        acc.x += w * xv.x; acc.y += w * xv.y;
                        acc.z += w * xv.z; acc.w += w * xv.w;
                    }
                }
            }
        }
        float di = dis_of(pk);
        if constexpr (H) {
            acc.x = di * (di * (float)hi[0] + acc.x);
            acc.y = di * (di * (float)hi[1] + acc.y);
            acc.z = di * (di * (float)hi[2] + acc.z);
            acc.w = di * (di * (float)hi[3] + acc.w);
        } else {
            acc.x = di * (di * xi.x + acc.x);
            acc.y = di * (di * xi.y + acc.y);
            acc.z = di * (di * xi.z + acc.z);
            acc.w = di * (di * xi.w + acc.w);
        }
    }
    Ast4[grp * 16 + ((j + (grp >> 2)) & 15)] = acc;   // swizzled slot
    __syncthreads();                   // covers Bs staging + Ast tile

    // Phase 2: 16x64 mini-GEMM (thread: row=grp', out-chs 4j..4j+3)
    int row = tid >> 4;
    int cg  = tid & 15;
    float4 oacc = ((const float4*)bias)[cg];
#pragma unroll 4
    for (int kc = 0; kc < 16; ++kc) {
        float4 a4 = Ast4[row * 16 + ((kc + (row >> 2)) & 15)];
        int cp = 4 * ((cg + kc) & 15);             // read swizzle matches staging
        float4 b0 = *(const float4*)&Bs[(4 * kc + 0) * 64 + cp];
        float4 b1 = *(const float4*)&Bs[(4 * kc + 1) * 64 + cp];
        float4 b2 = *(const float4*)&Bs[(4 * kc + 2) * 64 + cp];
        float4 b3 = *(const float4*)&Bs[(4 * kc + 3) * 64 + cp];
        oacc.x += a4.x * b0.x + a4.y * b1.x + a4.z * b2.x + a4.w * b3.x;
        oacc.y += a4.x * b0.y + a4.y * b1.y + a4.z * b2.y + a4.w * b3.y;
        oacc.z += a4.x * b0.z + a4.y * b1.z + a4.z * b2.z + a4.w * b3.z;
        oacc.w += a4.x * b0.w + a4.y * b1.w + a4.z * b2.w + a4.w * b3.w;
    }
    int r = i0 + row;
    if (r < n) ((float4*)out)[r * 16 + cg] = oacc;
}

extern "C" void kernel_launch(void* const* d_in, const int* in_sizes, int n_in,
                              void* d_out, int out_size, void* d_ws, size_t ws_size,
                              hipStream_t stream) {
    const float* x    = (const float*)d_in[0];
    const int*   ei   = (const int*)d_in[1];   // [2*E] flat: rows then cols
    const float* ew   = (const float*)d_in[2];
    const float* W    = (const float*)d_in[3];
    const float* bias = (const float*)d_in[4];
    float* out = (float*)d_out;

    int n  = in_sizes[0] / D;   // 100000
    int nE = in_sizes[2];       // 1000000
    const int* rowi = ei;
    const int* coli = ei + nE;

    // workspace: packed | spillCnt | slots | spill | xh(fp16)
    char* w = (char*)d_ws;
    unsigned long long* packed = (unsigned long long*)w; w += (size_t)n * 8;
    int* spillCnt = (int*)w;                             w += 64;
    unsigned int* slots = (unsigned int*)w;              w += (size_t)n * K * 4;
    int4* spill = (int4*)w;                              w += (size_t)SPILLCAP * 16;
    _Float16* xh = (_Float16*)w;

    size_t need = (size_t)n * 8 + 64 + (size_t)n * K * 4 + (size_t)SPILLCAP * 16
                + (size_t)n * D * 2;
    int useH = ws_size >= need ? 1 : 0;

    int gE = (nE + 255) / 256;
    int buildBlocks = gE * 8;
    int nv = n * D / 8;         // 800000 half8s
    int prepBlocks = useH ? (nv + 255) / 256 : 0;   // leading blocks
    int gT = (n + 15) / 16;     // 6250 blocks: 16 nodes/block, 1 node/group

    hipMemsetAsync(packed, 0, (size_t)n * 8 + 64, stream);   // packed + spillCnt
    k_build<<<prepBlocks + buildBlocks, 256, 0, stream>>>(
        rowi, coli, ew, packed, slots, spill, spillCnt, nE,
        prepBlocks, (const float4*)x, (half8*)xh, nv);
    if (useH)
        k_gather_gemm<true><<<gT, 256, 0, stream>>>(x, xh, packed, slots, spill, spillCnt, W, bias, out, n);
    else
        k_gather_gemm<false><<<gT, 256, 0, stream>>>(x, xh, packed, slots, spill, spillCnt, W, bias, out, n);
}